// Round 1
// baseline (413.358 us; speedup 1.0000x reference)
//
#include <hip/hip_runtime.h>
#include <stdint.h>

#define BB 32
#define LL 1024
#define CC 512
#define NN (BB * LL)      // 32768 positions
#define NLEVS 4
#define OUTD 11
#define LPAD 8            // zero pad rows per sequence (>= max dilation)
#define LROWS (LL + LPAD) // 1032 padded rows per sequence

typedef __attribute__((ext_vector_type(8))) short bf16x8;
typedef __attribute__((ext_vector_type(4))) float f32x4;

static __device__ __forceinline__ unsigned short f2bf(float f) {
    union { float f; uint32_t u; } v; v.f = f;
    uint32_t u = v.u;
    uint32_t r = (u + 0x7fffu + ((u >> 16) & 1u)) >> 16;  // RNE
    return (unsigned short)r;
}
static __device__ __forceinline__ float bf2f(unsigned short h) {
    union { uint32_t u; float f; } v; v.u = ((uint32_t)h) << 16;
    return v.f;
}

// async 16B global -> LDS (wave-uniform LDS base + lane*16)
static __device__ __forceinline__ void llds16(const unsigned short* g, unsigned short* l) {
    __builtin_amdgcn_global_load_lds(
        (const __attribute__((address_space(1))) unsigned int*)g,
        (__attribute__((address_space(3))) unsigned int*)l, 16, 0, 0);
}

// Fused prep: pack_w | embed | zero_pad | pack_dw, selected by block range.
__global__ __launch_bounds__(256) void prep_kernel(
    const int* __restrict__ x, const float* __restrict__ emb,
    const float* __restrict__ w1, const float* __restrict__ w2,
    const float* __restrict__ dw,
    unsigned short* __restrict__ Hb0, unsigned short* __restrict__ Hb1,
    unsigned short* __restrict__ WpT, unsigned short* __restrict__ dwp)
{
    int b = blockIdx.x;
    if (b < 16384) {
        // WpT[cv][j][co][h]; kidx=j*8+h; kidx<512 -> tap k=1 (current), else k=0
        int e = b * 256 + threadIdx.x;
        int cv = e >> 19;
        int r = e & 524287;
        int j = r >> 12;
        int co = (r >> 3) & 511;
        int h = r & 7;
        int kidx = j * 8 + h;
        int k = (kidx < 512) ? 1 : 0;
        int ci = kidx & 511;
        int lvl = cv >> 1;
        const float* w = (cv & 1) ? w2 : w1;
        WpT[e] = f2bf(w[(((size_t)(lvl * 512 + co) * 512) + ci) * 2 + k]);
    } else if (b < 24576) {
        int t = (b - 16384) * 256 + threadIdx.x;
        int n = t >> 6;
        int c8 = (t & 63) * 8;
        int idx = x[n];
        const float* src = emb + (size_t)idx * CC + c8;
        float4 v0 = *(const float4*)src;
        float4 v1 = *(const float4*)(src + 4);
        ushort4 a, bb;
        a.x = f2bf(v0.x); a.y = f2bf(v0.y); a.z = f2bf(v0.z); a.w = f2bf(v0.w);
        bb.x = f2bf(v1.x); bb.y = f2bf(v1.y); bb.z = f2bf(v1.z); bb.w = f2bf(v1.w);
        int prow = (n >> 10) * LROWS + LPAD + (n & (LL - 1));
        unsigned short* dst = Hb0 + (size_t)prow * CC + c8;
        *(ushort4*)dst = a;
        *(ushort4*)(dst + 4) = bb;
    } else if (b < 24704) {
        int t = (b - 24576) * 256 + threadIdx.x;   // 32768 uint4 stores
        unsigned short* base = (t >> 14) ? Hb1 : Hb0;
        int rem = t & 16383;
        int p = rem >> 9;
        int q = rem & 511;
        size_t off = (size_t)p * (LROWS * CC) + (size_t)q * 8;
        *(uint4*)(base + off) = (uint4){0u, 0u, 0u, 0u};
    } else {
        int e = (b - 24704) * 256 + threadIdx.x;   // 8192 halves
        int jb = e >> 7;
        int o = (e >> 3) & 15;
        int j = e & 7;
        dwp[e] = f2bf((o < OUTD) ? dw[o * CC + jb * 8 + j] : 0.f);
    }
}

// GEMM: out[n][co] = act( A-window . W + bias ), all activations bf16.
// 128n x 128co tile, BK=64/buffer. PAIR-PRIVATE staging, SELF-SUFFICIENT waves:
// the two waves of a pair (same wm, wn=0/64) consume identical A rows, and a
// 64-row stripe + 8 halo rows = 72 rows fits a 9216 B slot. Each wave issues
// ALL 9 staging segments of its pair slot itself (duplicate issue with its
// partner -- same bytes, race-benign, L2 absorbs the re-read). Therefore:
//  - buffer readiness = own vmcnt drain only. NO cross-wave ready spin.
//  - only remaining handshake: partner "done with slot" flag (width 2),
//    checked before overwriting a slot (it+1 targets the slot read at it-1).
// Per wave/it: spin partner flag[it-1] -> issue 9 A loads for it+1 ->
// s_waitcnt vmcnt(9) (drains own it loads; it+1's stay in flight through the
// whole compute phase) -> compute(it) -> set own flag[it]. No __syncthreads
// in the loop => no forced vmcnt(0) drain (the m97-plateau stall).
// 16x16x32 MFMA 4x4/wave; 128-B-pitch XOR-swizzled LDS (zero-conflict
// geometry preserved: pair stripe wm=64 == 0 mod 8). B direct from global
// (k-major WpT), 1-step register prefetch. XCD swizzle: 4 co-blocks of an
// n-window land on one XCD. HAS_RES: v = relu(relu(acc+b) + res_bf16);
// in-place-safe (lane-owned elems).
#define PSEG 9
#define PBUFH (72 * 64)   // halves per pair slot: 72 rows x 64 = 9216 B
template <bool HAS_RES>
__global__ __launch_bounds__(256, 4) void conv_gemm(
    const unsigned short* __restrict__ Ain, const unsigned short* __restrict__ WpT,
    const float* __restrict__ bias, const unsigned short* __restrict__ resB,
    unsigned short* __restrict__ OutB, int d)
{
    __shared__ unsigned short sA[2 * 2 * PBUFH];  // [pair][slot][72*64]
    __shared__ int s_flag[4][8];                  // [wave][it] done-with-slot

    const int tid = threadIdx.x;
    const int wave = tid >> 6, lane = tid & 63;
    const int pair = wave >> 1;

    const int bid = blockIdx.x;               // 0..1023
    const int xcd = bid & 7;
    const int local = bid >> 3;               // 0..127
    const int cb = local >> 5;                // 0..3
    const int nb = xcd + 8 * (local & 31);    // 0..255
    const int co0 = cb * 128;
    const int n0 = nb * 128;

    const int rbase = (n0 >> 10) * LROWS + LPAD + (n0 & (LL - 1));
    const int wm = pair * 64;                  // pair n-stripe
    const int wn = (wave & 1) * 64;            // wave co-stripe
    const int lm = lane & 15, quad = lane >> 4;

    // staging lane decomposition: 8 rows x 8 chunks of 16B per llds16 (1 KB)
    const int r8 = lane >> 3;
    const int c8 = lane & 7;

    if (tid < 32) ((int*)s_flag)[tid] = 0;
    __syncthreads();

    f32x4 acc[4][4];
#pragma unroll
    for (int i = 0; i < 4; ++i)
#pragma unroll
        for (int j = 0; j < 4; ++j) acc[i][j] = (f32x4){0.f, 0.f, 0.f, 0.f};

    unsigned short* pb = sA + pair * (2 * PBUFH);
    const unsigned short* gAb =
        Ain + (size_t)(rbase - 8 + wm + r8) * CC + (c8 ^ r8) * 8;

    // issue ALL 9 segments of ci-block `it` into this pair's slot it&1
    auto issue = [&](int it) {
        const unsigned short* gA = gAb + it * 64;
        unsigned short* lb = pb + (it & 1) * PBUFH;
#pragma unroll
        for (int seg = 0; seg < PSEG; ++seg)
            llds16(gA + (size_t)seg * 8 * CC, lb + seg * 512);
    };

    issue(0);

    for (int it = 0; it < 8; ++it) {
        if (it < 7) {
            if (it >= 1) {
                // slot (it+1)&1 was last read by partner at it-1
                volatile int* vp = &s_flag[wave ^ 1][it - 1];
                while (*vp == 0) __builtin_amdgcn_s_sleep(1);
            }
            issue(it + 1);
            // outstanding = 9 (it, oldest) + 9 (it+1): drain own it loads only
            __builtin_amdgcn_s_waitcnt(0xF79);                 // vmcnt(9)
        } else {
            __builtin_amdgcn_s_waitcnt(0xF70);                 // vmcnt(0)
        }
        __asm__ volatile("" ::: "memory");

        const unsigned short* buf = pb + (it & 1) * PBUFH;
        const int jb0 = it * 8;

        // step s = t*2 + ks: t = tap (0 current, 1 past), ks = K=32 slice
        auto loadA = [&](int s, bf16x8* af) {
            const int t = s >> 1, ks = s & 1;
            const int shift = t ? d : 0;
            const int rowoff = 8 - shift;
            const int key = (8 - shift + lm) & 7;
            const int cpos = ((ks * 4 + quad) ^ key);
#pragma unroll
            for (int mt = 0; mt < 4; ++mt)
                af[mt] = *(const bf16x8*)&buf[(rowoff + mt * 16 + lm) * 64 + cpos * 8];
        };
        auto loadB = [&](int s, bf16x8* bf) {
            const int t = s >> 1, ks = s & 1;
            const int jb = t * 64 + jb0 + ks * 4 + quad;
            const unsigned short* bbase = WpT + ((size_t)jb * 512 + co0 + wn + lm) * 8;
#pragma unroll
            for (int nt = 0; nt < 4; ++nt)
                bf[nt] = *(const bf16x8*)(bbase + (size_t)nt * 16 * 8);
        };

        bf16x8 afc[4], bfc[4], afn[4], bfn[4];
        loadA(0, afc);
        loadB(0, bfc);
#pragma unroll
        for (int s = 0; s < 4; ++s) {
            if (s < 3) { loadA(s + 1, afn); loadB(s + 1, bfn); }
#pragma unroll
            for (int mt = 0; mt < 4; ++mt)
#pragma unroll
                for (int nt = 0; nt < 4; ++nt)
                    acc[mt][nt] = __builtin_amdgcn_mfma_f32_16x16x32_bf16(
                        afc[mt], bfc[nt], acc[mt][nt], 0, 0, 0);
            if (s < 3) {
#pragma unroll
                for (int q2 = 0; q2 < 4; ++q2) { afc[q2] = afn[q2]; bfc[q2] = bfn[q2]; }
            }
        }

        __asm__ volatile("" ::: "memory");
        if (lane == 0) *(volatile int*)&s_flag[wave][it] = 1;
    }

    // epilogue: C/D layout col(co)=lane&15, row(n)=quad*4+reg
    float bv[4];
#pragma unroll
    for (int nt = 0; nt < 4; ++nt) bv[nt] = bias[co0 + wn + nt * 16 + lm];

#pragma unroll
    for (int mt = 0; mt < 4; ++mt) {
        int prow0 = rbase + wm + mt * 16 + quad * 4;
#pragma unroll
        for (int nt = 0; nt < 4; ++nt) {
            int co = co0 + wn + nt * 16 + lm;
#pragma unroll
            for (int r = 0; r < 4; ++r) {
                size_t off = (size_t)(prow0 + r) * CC + co;
                float v = acc[mt][nt][r] + bv[nt];
                v = fmaxf(v, 0.f);
                if (HAS_RES) {
                    v += bf2f(resB[off]);
                    v = fmaxf(v, 0.f);
                }
                OutB[off] = f2bf(v);
            }
        }
    }
}

// decode as per-wave MFMA mini-GEMM: M=16 n, N=16 o (11 real), K=512.
__global__ __launch_bounds__(256) void decode_kernel(
    const unsigned short* __restrict__ H, const unsigned short* __restrict__ dwp,
    const float* __restrict__ db, const int* __restrict__ mask,
    float* __restrict__ out)
{
    const int wave = threadIdx.x >> 6, lane = threadIdx.x & 63;
    const int lm = lane & 15, quad = lane >> 4;
    const int n0 = blockIdx.x * 64 + wave * 16;    // 64-aligned: no seq crossing
    const int prow = ((n0 + lm) >> 10) * LROWS + LPAD + ((n0 + lm) & (LL - 1));

    f32x4 acc = (f32x4){0.f, 0.f, 0.f, 0.f};
#pragma unroll
    for (int ks = 0; ks < 16; ++ks) {
        bf16x8 af = *(const bf16x8*)&H[(size_t)prow * CC + ks * 32 + quad * 8];
        bf16x8 bf = *(const bf16x8*)&dwp[((size_t)(ks * 4 + quad) * 16 + lm) * 8];
        acc = __builtin_amdgcn_mfma_f32_16x16x32_bf16(af, bf, acc, 0, 0, 0);
    }

    if (lm < OUTD) {
        float bo = db[lm];
#pragma unroll
        for (int r = 0; r < 4; ++r) {
            int n = n0 + quad * 4 + r;
            float v = (mask[n] != 0) ? (acc[r] + bo) : 0.f;
            out[(size_t)n * OUTD + lm] = v;
        }
    }
}

extern "C" void kernel_launch(void* const* d_in, const int* in_sizes, int n_in,
                              void* d_out, int out_size, void* d_ws, size_t ws_size,
                              hipStream_t stream)
{
    const int* x = (const int*)d_in[0];
    const int* mask = (const int*)d_in[1];   // jnp bool_ staged as int32
    const float* emb = (const float*)d_in[2];
    const float* w1 = (const float*)d_in[3];
    const float* b1 = (const float*)d_in[4];
    const float* w2 = (const float*)d_in[5];
    const float* b2 = (const float*)d_in[6];
    const float* dw = (const float*)d_in[7];
    const float* db = (const float*)d_in[8];
    float* out = (float*)d_out;

    char* ws = (char*)d_ws;
    const size_t HBB = (size_t)BB * LROWS * CC * 2;       // 33.8 MB (padded bf16)
    unsigned short* Hb0 = (unsigned short*)ws;
    unsigned short* Hb1 = (unsigned short*)(ws + HBB);
    unsigned short* WpT = (unsigned short*)(ws + 2 * HBB); // k-major bf16 weights, 8 MB
    unsigned short* dwp = (unsigned short*)(ws + 2 * HBB + (size_t)NLEVS * 2 * CC * 1024 * 2);

    prep_kernel<<<24736, 256, 0, stream>>>(x, emb, w1, w2, dw, Hb0, Hb1, WpT, dwp);

    const int grid = (CC / 128) * (NN / 128);   // 4 * 256 = 1024 blocks = 4/CU
    for (int i = 0; i < NLEVS; ++i) {
        int d = 1 << i;
        const unsigned short* W1 = WpT + (size_t)(i * 2 + 0) * CC * 1024;
        const unsigned short* W2 = WpT + (size_t)(i * 2 + 1) * CC * 1024;
        // conv1: A=Hb0 -> Hb1
        conv_gemm<false><<<grid, 256, 0, stream>>>(Hb0, W1, b1 + i * CC, nullptr, Hb1, d);
        // conv2: A=Hb1, res=Hb0 (bf16), out=Hb0 (in place, lane-owned)
        conv_gemm<true><<<grid, 256, 0, stream>>>(Hb1, W2, b2 + i * CC, Hb0, Hb0, d);
    }
    decode_kernel<<<NN / 64, 256, 0, stream>>>(Hb0, dwp, db, mask, out);
}

// Round 3
// 394.011 us; speedup vs baseline: 1.0491x; 1.0491x over previous
//
#include <hip/hip_runtime.h>
#include <stdint.h>

#define BB 32
#define LL 1024
#define CC 512
#define NN (BB * LL)      // 32768 positions
#define NLEVS 4
#define OUTD 11
#define LPAD 8            // zero pad rows per sequence (>= max dilation)
#define LROWS (LL + LPAD) // 1032 padded rows per sequence

typedef __attribute__((ext_vector_type(8))) short bf16x8;
typedef __attribute__((ext_vector_type(4))) float f32x4;

static __device__ __forceinline__ unsigned short f2bf(float f) {
    union { float f; uint32_t u; } v; v.f = f;
    uint32_t u = v.u;
    uint32_t r = (u + 0x7fffu + ((u >> 16) & 1u)) >> 16;  // RNE
    return (unsigned short)r;
}
static __device__ __forceinline__ float bf2f(unsigned short h) {
    union { uint32_t u; float f; } v; v.u = ((uint32_t)h) << 16;
    return v.f;
}

// async 16B global -> LDS (wave-uniform LDS base + lane*16)
static __device__ __forceinline__ void llds16(const unsigned short* g, unsigned short* l) {
    __builtin_amdgcn_global_load_lds(
        (const __attribute__((address_space(1))) unsigned int*)g,
        (__attribute__((address_space(3))) unsigned int*)l, 16, 0, 0);
}

// Fused prep: pack_w | embed | zero_pad | pack_dw, selected by block range.
__global__ __launch_bounds__(256) void prep_kernel(
    const int* __restrict__ x, const float* __restrict__ emb,
    const float* __restrict__ w1, const float* __restrict__ w2,
    const float* __restrict__ dw,
    unsigned short* __restrict__ Hb0, unsigned short* __restrict__ Hb1,
    unsigned short* __restrict__ WpT, unsigned short* __restrict__ dwp)
{
    int b = blockIdx.x;
    if (b < 16384) {
        // WpT[cv][j][co][h]; kidx=j*8+h; kidx<512 -> tap k=1 (current), else k=0
        int e = b * 256 + threadIdx.x;
        int cv = e >> 19;
        int r = e & 524287;
        int j = r >> 12;
        int co = (r >> 3) & 511;
        int h = r & 7;
        int kidx = j * 8 + h;
        int k = (kidx < 512) ? 1 : 0;
        int ci = kidx & 511;
        int lvl = cv >> 1;
        const float* w = (cv & 1) ? w2 : w1;
        WpT[e] = f2bf(w[(((size_t)(lvl * 512 + co) * 512) + ci) * 2 + k]);
    } else if (b < 24576) {
        int t = (b - 16384) * 256 + threadIdx.x;
        int n = t >> 6;
        int c8 = (t & 63) * 8;
        int idx = x[n];
        const float* src = emb + (size_t)idx * CC + c8;
        float4 v0 = *(const float4*)src;
        float4 v1 = *(const float4*)(src + 4);
        ushort4 a, bb;
        a.x = f2bf(v0.x); a.y = f2bf(v0.y); a.z = f2bf(v0.z); a.w = f2bf(v0.w);
        bb.x = f2bf(v1.x); bb.y = f2bf(v1.y); bb.z = f2bf(v1.z); bb.w = f2bf(v1.w);
        int prow = (n >> 10) * LROWS + LPAD + (n & (LL - 1));
        unsigned short* dst = Hb0 + (size_t)prow * CC + c8;
        *(ushort4*)dst = a;
        *(ushort4*)(dst + 4) = bb;
    } else if (b < 24704) {
        int t = (b - 24576) * 256 + threadIdx.x;   // 32768 uint4 stores
        unsigned short* base = (t >> 14) ? Hb1 : Hb0;
        int rem = t & 16383;
        int p = rem >> 9;
        int q = rem & 511;
        size_t off = (size_t)p * (LROWS * CC) + (size_t)q * 8;
        *(uint4*)(base + off) = (uint4){0u, 0u, 0u, 0u};
    } else {
        int e = (b - 24704) * 256 + threadIdx.x;   // 8192 halves
        int jb = e >> 7;
        int o = (e >> 3) & 15;
        int j = e & 7;
        dwp[e] = f2bf((o < OUTD) ? dw[o * CC + jb * 8 + j] : 0.f);
    }
}

// GEMM: out[n][co] = act( A-window . W + bias ), all activations bf16.
// 256n x 128co tile, BK=64/buffer, grid 512 = 2 blocks/CU = 2 waves/SIMD.
// Round-2 rationale: at the old 128x128/4-block tile the kernel was bound by
// (a) L2 request pressure (~6400 lines/CU/it, B loaded 2x, A pair-duplicated)
// and (b) vmcnt ENTANGLEMENT: B register loads issued after the staging
// global_load_lds of it+1 can only be consumed by draining that staging
// (in-order vmcnt retirement) -- the HBM prefetch never actually stayed in
// flight. Fix: preload ALL of B for the it into registers BEFORE the staging
// issue (64 VGPRs) -- affordable only at 2 waves/SIMD (256-reg budget).
// Round-3 hardening: A-fragments processed in two mt-halves (af[4], not
// af[8]) to keep live regs ~235 < 256 (no spill risk; B frags are reused
// across mt so the MFMA schedule is unchanged).
// Wave (wr,wc): wr=wave>>1 owns a 128-row n-stripe, wc=wave&1 a 64-co stripe;
// acc[8][4]. Pair (same wr) shares a private 136-row double-buffered LDS
// stripe; each wave issues ALL 17 staging segments itself (duplicate issue,
// race-benign -- identical bytes) so buffer readiness = own vmcnt only.
// Partner "done with slot" flag guards slot reuse (it+1 overwrites the slot
// read at it-1). Per it: vmcnt(0) [staging(it), landed during prev compute]
// -> load 16 B frags (L2-hot WpT) -> spin partner flag -> issue staging(it+1)
// -> compute 4 steps x 32 MFMA from LDS-A x reg-B (B waits leave staging in
// flight). 16x16x32 MFMA; 128-B-pitch XOR-swizzled LDS (zero-conflict,
// stripe base 128 == 0 mod 8). XCD swizzle: 4 co-blocks of an n-window share
// an XCD. HAS_RES: v = relu(relu(acc+b) + res_bf16); in-place-safe.
#define PSEG 17
#define SROWS 136
#define PBUFH (SROWS * 64)   // halves per pair slot: 136 rows x 64 = 17408 B
template <bool HAS_RES>
__global__ __launch_bounds__(256, 2) void conv_gemm(
    const unsigned short* __restrict__ Ain, const unsigned short* __restrict__ WpT,
    const float* __restrict__ bias, const unsigned short* __restrict__ resB,
    unsigned short* __restrict__ OutB, int d)
{
    __shared__ unsigned short sA[2 * 2 * PBUFH];  // [pair][slot][136*64]
    __shared__ int s_flag[4][8];                  // [wave][it] done-with-slot

    const int tid = threadIdx.x;
    const int wave = tid >> 6, lane = tid & 63;
    const int pairi = wave >> 1;

    const int bid = blockIdx.x;               // 0..511
    const int xcd = bid & 7;
    const int local = bid >> 3;               // 0..63
    const int cb = local >> 4;                // 0..3
    const int nb = xcd + 8 * (local & 15);    // 0..127
    const int co0 = cb * 128;
    const int n0 = nb * 256;                  // 256-aligned: never crosses seq

    const int rbase = (n0 >> 10) * LROWS + LPAD + (n0 & (LL - 1));
    const int wm = pairi * 128;                // pair n-stripe
    const int wn = (wave & 1) * 64;            // wave co-stripe
    const int lm = lane & 15, quad = lane >> 4;

    // staging lane decomposition: 8 rows x 8 chunks of 16B per llds16 (1 KB)
    const int r8 = lane >> 3;
    const int c8 = lane & 7;

    if (tid < 32) ((int*)s_flag)[tid] = 0;
    __syncthreads();

    f32x4 acc[8][4];
#pragma unroll
    for (int i = 0; i < 8; ++i)
#pragma unroll
        for (int j = 0; j < 4; ++j) acc[i][j] = (f32x4){0.f, 0.f, 0.f, 0.f};

    unsigned short* pb = sA + pairi * (2 * PBUFH);
    const unsigned short* gAb =
        Ain + (size_t)(rbase - 8 + wm + r8) * CC + (c8 ^ r8) * 8;

    // issue ALL 17 segments of ci-block `it` into this pair's slot it&1
    auto issue = [&](int it) {
        const unsigned short* gA = gAb + it * 64;
        unsigned short* lb = pb + (it & 1) * PBUFH;
#pragma unroll
        for (int seg = 0; seg < PSEG; ++seg)
            llds16(gA + (size_t)seg * 8 * CC, lb + seg * 512);
    };

    issue(0);

    bf16x8 breg[4][4];

    for (int it = 0; it < 8; ++it) {
        // own staging(it) is the only outstanding vmem; it had the whole
        // previous compute phase (> HBM latency) to land.
        __builtin_amdgcn_s_waitcnt(0xF70);                     // vmcnt(0)
        __asm__ volatile("" ::: "memory");

        const int jb0 = it * 8;
        // ALL B loads for this it BEFORE the next staging issue: anything
        // issued after a global_load_lds can't be waited for without draining
        // it (in-order vmcnt retirement).
#pragma unroll
        for (int s = 0; s < 4; ++s) {
            const int t = s >> 1, ks = s & 1;
            const int jb = t * 64 + jb0 + ks * 4 + quad;
            const unsigned short* bbase = WpT + ((size_t)jb * 512 + co0 + wn + lm) * 8;
#pragma unroll
            for (int nt = 0; nt < 4; ++nt)
                breg[s][nt] = *(const bf16x8*)(bbase + (size_t)nt * 16 * 8);
        }
        __asm__ volatile("" ::: "memory");

        if (it < 7) {
            if (it >= 1) {
                // slot (it+1)&1 was last read by partner at it-1
                volatile int* vp = &s_flag[wave ^ 1][it - 1];
                while (*vp == 0) __builtin_amdgcn_s_sleep(1);
            }
            issue(it + 1);   // stays in flight through the whole compute phase
        }
        __asm__ volatile("" ::: "memory");

        const unsigned short* buf = pb + (it & 1) * PBUFH;

        // step s = t*2 + ks: t = tap (0 current, 1 past), ks = K=32 slice.
        // Two mt-halves of 4 keep the live A-frag set at 16 VGPRs.
#pragma unroll
        for (int s = 0; s < 4; ++s) {
            const int t = s >> 1, ks = s & 1;
            const int shift = t ? d : 0;
            const int rowoff = 8 - shift;
            const int key = (8 - shift + lm) & 7;
            const int cpos = ((ks * 4 + quad) ^ key);
#pragma unroll
            for (int half = 0; half < 2; ++half) {
                bf16x8 af[4];
#pragma unroll
                for (int q = 0; q < 4; ++q) {
                    const int mt = half * 4 + q;
                    af[q] = *(const bf16x8*)&buf[(rowoff + mt * 16 + lm) * 64 + cpos * 8];
                }
#pragma unroll
                for (int q = 0; q < 4; ++q)
#pragma unroll
                    for (int nt = 0; nt < 4; ++nt)
                        acc[half * 4 + q][nt] = __builtin_amdgcn_mfma_f32_16x16x32_bf16(
                            af[q], breg[s][nt], acc[half * 4 + q][nt], 0, 0, 0);
            }
        }

        __asm__ volatile("" ::: "memory");
        if (lane == 0) *(volatile int*)&s_flag[wave][it] = 1;
    }

    // epilogue: C/D layout col(co)=lane&15, row(n)=quad*4+reg
    float bv[4];
#pragma unroll
    for (int nt = 0; nt < 4; ++nt) bv[nt] = bias[co0 + wn + nt * 16 + lm];

#pragma unroll
    for (int mt = 0; mt < 8; ++mt) {
        int prow0 = rbase + wm + mt * 16 + quad * 4;
#pragma unroll
        for (int nt = 0; nt < 4; ++nt) {
            int co = co0 + wn + nt * 16 + lm;
#pragma unroll
            for (int r = 0; r < 4; ++r) {
                size_t off = (size_t)(prow0 + r) * CC + co;
                float v = acc[mt][nt][r] + bv[nt];
                v = fmaxf(v, 0.f);
                if (HAS_RES) {
                    v += bf2f(resB[off]);
                    v = fmaxf(v, 0.f);
                }
                OutB[off] = f2bf(v);
            }
        }
    }
}

// decode as per-wave MFMA mini-GEMM: M=16 n, N=16 o (11 real), K=512.
__global__ __launch_bounds__(256) void decode_kernel(
    const unsigned short* __restrict__ H, const unsigned short* __restrict__ dwp,
    const float* __restrict__ db, const int* __restrict__ mask,
    float* __restrict__ out)
{
    const int wave = threadIdx.x >> 6, lane = threadIdx.x & 63;
    const int lm = lane & 15, quad = lane >> 4;
    const int n0 = blockIdx.x * 64 + wave * 16;    // 64-aligned: no seq crossing
    const int prow = ((n0 + lm) >> 10) * LROWS + LPAD + ((n0 + lm) & (LL - 1));

    f32x4 acc = (f32x4){0.f, 0.f, 0.f, 0.f};
#pragma unroll
    for (int ks = 0; ks < 16; ++ks) {
        bf16x8 af = *(const bf16x8*)&H[(size_t)prow * CC + ks * 32 + quad * 8];
        bf16x8 bf = *(const bf16x8*)&dwp[((size_t)(ks * 4 + quad) * 16 + lm) * 8];
        acc = __builtin_amdgcn_mfma_f32_16x16x32_bf16(af, bf, acc, 0, 0, 0);
    }

    if (lm < OUTD) {
        float bo = db[lm];
#pragma unroll
        for (int r = 0; r < 4; ++r) {
            int n = n0 + quad * 4 + r;
            float v = (mask[n] != 0) ? (acc[r] + bo) : 0.f;
            out[(size_t)n * OUTD + lm] = v;
        }
    }
}

extern "C" void kernel_launch(void* const* d_in, const int* in_sizes, int n_in,
                              void* d_out, int out_size, void* d_ws, size_t ws_size,
                              hipStream_t stream)
{
    const int* x = (const int*)d_in[0];
    const int* mask = (const int*)d_in[1];   // jnp bool_ staged as int32
    const float* emb = (const float*)d_in[2];
    const float* w1 = (const float*)d_in[3];
    const float* b1 = (const float*)d_in[4];
    const float* w2 = (const float*)d_in[5];
    const float* b2 = (const float*)d_in[6];
    const float* dw = (const float*)d_in[7];
    const float* db = (const float*)d_in[8];
    float* out = (float*)d_out;

    char* ws = (char*)d_ws;
    const size_t HBB = (size_t)BB * LROWS * CC * 2;       // 33.8 MB (padded bf16)
    unsigned short* Hb0 = (unsigned short*)ws;
    unsigned short* Hb1 = (unsigned short*)(ws + HBB);
    unsigned short* WpT = (unsigned short*)(ws + 2 * HBB); // k-major bf16 weights, 8 MB
    unsigned short* dwp = (unsigned short*)(ws + 2 * HBB + (size_t)NLEVS * 2 * CC * 1024 * 2);

    prep_kernel<<<24736, 256, 0, stream>>>(x, emb, w1, w2, dw, Hb0, Hb1, WpT, dwp);

    const int grid = (CC / 128) * (NN / 256);   // 4 * 128 = 512 blocks = 2/CU
    for (int i = 0; i < NLEVS; ++i) {
        int d = 1 << i;
        const unsigned short* W1 = WpT + (size_t)(i * 2 + 0) * CC * 1024;
        const unsigned short* W2 = WpT + (size_t)(i * 2 + 1) * CC * 1024;
        // conv1: A=Hb0 -> Hb1
        conv_gemm<false><<<grid, 256, 0, stream>>>(Hb0, W1, b1 + i * CC, nullptr, Hb1, d);
        // conv2: A=Hb1, res=Hb0 (bf16), out=Hb0 (in place, lane-owned)
        conv_gemm<true><<<grid, 256, 0, stream>>>(Hb1, W2, b2 + i * CC, Hb0, Hb0, d);
    }
    decode_kernel<<<NN / 64, 256, 0, stream>>>(Hb0, dwp, db, mask, out);
}